// Round 2
// baseline (22863.754 us; speedup 1.0000x reference)
//
#include <hip/hip_runtime.h>

// LSTM: T=2048, B=32, E=512, H=512, fp32 in/out.
// R2: shrink the sync domain. 32 WGs x 512 threads (8 waves = 2 Mtiles x 4 Ntiles),
// each WG owns 16 h-columns (64 packed gate cols, 142KB dynamic LDS).
//   - flags 128 -> 32 (poll = 2 cache lines, 16 active lanes)
//   - straggler pool 128 -> 32 WGs
//   - same per-wave MFMA work as R1 (16 emb + 16 h MFMAs, K=1024)
//   - keeps R1 protocol: hoisted emb-MFMA before poll, wave-local LDS transpose
//     (no barrier), ONE __syncthreads per step (pre-publish vmcnt drain),
//     out[] stores post-publish.

#define T_STEPS 2048
#define BATCH   32
#define EDIM    512
#define HDIM    512
#define NW      32    // recurrent workgroups
#define NJH     16    // h-columns per WG
#define NCOL    64    // packed gate columns per WG (4 gates * NJH)
#define WG_THREADS 512
#define BSTRIDE 1032  // 1024 + 8 pad (16B-aligned rows, kills LDS bank conflicts)

typedef unsigned int       u32;
typedef unsigned long long u64;
typedef unsigned short     u16;
typedef float  floatx4 __attribute__((ext_vector_type(4)));
typedef __bf16 bf16x8  __attribute__((ext_vector_type(8)));

#define BLDS_BYTES (NCOL * BSTRIDE * 2)          // 132096
#define WBUF_OFF   BLDS_BYTES                    // 16B aligned
#define LDS_BYTES  (BLDS_BYTES + 8 * 16 * 20 * 4) // + wbuf[8][16][20] = 142336

union BF16U { __bf16 b; u16 u; };

__device__ __forceinline__ u16 f2bf(float f) { BF16U x; x.b = (__bf16)f; return x.u; }

__device__ __forceinline__ float fast_sigmoid(float x) {
  return 1.0f / (1.0f + __expf(-x));
}
__device__ __forceinline__ float fast_tanh(float x) {
  float e = __expf(-2.0f * fabsf(x));       // e in (0,1], no overflow
  float t = (1.0f - e) / (1.0f + e);
  return x >= 0.0f ? t : -t;
}

// ---------------------------------------------------------------- phase 1
__global__ void lstm_prep(const float* __restrict__ emb, u16* __restrict__ embb,
                          const float* __restrict__ h0, u16* __restrict__ hb0,
                          u32* __restrict__ flags) {
  const size_t n4 = (size_t)T_STEPS * BATCH * EDIM / 4;
  size_t stride = (size_t)gridDim.x * blockDim.x;
  size_t gid = (size_t)blockIdx.x * blockDim.x + threadIdx.x;
  for (size_t i = gid; i < n4; i += stride) {
    float4 v = ((const float4*)emb)[i];
    ushort4 o;
    o.x = f2bf(v.x); o.y = f2bf(v.y); o.z = f2bf(v.z); o.w = f2bf(v.w);
    ((ushort4*)embb)[i] = o;
  }
  if (gid < (size_t)BATCH * HDIM) hb0[gid] = f2bf(h0[gid]);
  if (gid < NW) flags[gid] = 0u;
}

// ---------------------------------------------------------------- phase 2
__global__ void __launch_bounds__(WG_THREADS)
lstm_rec(const u16* __restrict__ embb,
         const float* __restrict__ c0,
         const float* __restrict__ Wx0, const float* __restrict__ Wh0, const float* __restrict__ b0,
         const float* __restrict__ Wx1, const float* __restrict__ Wh1, const float* __restrict__ b1,
         const float* __restrict__ Wx2, const float* __restrict__ Wh2, const float* __restrict__ b2,
         const float* __restrict__ Wx3, const float* __restrict__ Wh3, const float* __restrict__ b3,
         u16* __restrict__ hbuf,            // [2][BATCH*HDIM] bf16
         u32* __restrict__ flags,           // [NW]
         float* __restrict__ out) {
  extern __shared__ __align__(16) char dynlds[];
  __bf16 (*Blds)[BSTRIDE] = (__bf16(*)[BSTRIDE])dynlds;       // [64][1032] bf16
  float  (*wbuf)[16][20]  = (float(*)[16][20])(dynlds + WBUF_OFF); // [8 waves]

  const int tid    = threadIdx.x;
  const int w      = blockIdx.x;
  const int j0     = w * NJH;           // first h-column owned by this WG
  const int lane   = tid & 63;
  const int waveid = tid >> 6;          // 8 waves
  const int mtile  = waveid & 1;        // batch half (M-tile)
  const int ntile  = waveid >> 1;       // column quad group (N-tile)
  const int nlo    = lane & 15;
  const int q      = lane >> 4;
  const int mrow   = mtile * 16 + nlo;  // batch row this lane loads A for
  const int pbase  = ntile * 16;        // first packed col of this wave's B tile

  const float* Wx[4] = {Wx0, Wx1, Wx2, Wx3};
  const float* Wh[4] = {Wh0, Wh1, Wh2, Wh3};

  // ---- stage weight slice into LDS as bf16.
  // Packed col p = cq*16 + g*4 + cjl  <->  gate g, h-col j0 + cq*4 + cjl.
  // So N-tile `ntile` (= cq) holds ALL 4 gates for h-cols j0+ntile*4 .. +3,
  // making the epilogue wave-local.
  {
    const int kk = tid;                 // 512 threads cover K=512 in one pass
    for (int g = 0; g < 4; ++g) {
      for (int cq = 0; cq < 4; ++cq) {
        const float4 wxv = *(const float4*)(Wx[g] + (size_t)kk * HDIM + j0 + cq * 4);
        const float4 whv = *(const float4*)(Wh[g] + (size_t)kk * HDIM + j0 + cq * 4);
        const int p = cq * 16 + g * 4;
        Blds[p + 0][kk] = (__bf16)wxv.x;  Blds[p + 0][EDIM + kk] = (__bf16)whv.x;
        Blds[p + 1][kk] = (__bf16)wxv.y;  Blds[p + 1][EDIM + kk] = (__bf16)whv.y;
        Blds[p + 2][kk] = (__bf16)wxv.z;  Blds[p + 2][EDIM + kk] = (__bf16)whv.z;
        Blds[p + 3][kk] = (__bf16)wxv.w;  Blds[p + 3][EDIM + kk] = (__bf16)whv.w;
      }
    }
  }

  // ---- per-lane epilogue state: lane owns (batch row er, h column jg).
  // C layout: col = nlo, row-in-Mtile = q*4 + reg. Lane (q,nlo) epilogues
  // row er = mtile*16 + q*4 + (nlo>>2), local h-col cjl = nlo&3 — all 4 gate
  // values come from this wave's own accumulator tile (wave-local transpose).
  const int r0 = nlo >> 2;
  const int ej = nlo & 3;
  const int er = mtile * 16 + q * 4 + r0;     // batch row
  const int jg = j0 + ntile * 4 + ej;         // global h column
  float cst = c0[(size_t)er * HDIM + jg];
  const float bgv = b0[jg], biv = b1[jg], bfv = b2[jg], bov = b3[jg];

  __syncthreads();

  const u64* f8 = (const u64*)flags;  // lanes 0..15 x u64 = 32 flags

  for (int t = 0; t < T_STEPS; ++t) {
    // ---- x-part first: gates(pre) += emb_t @ Wx slice. No h_t dependence, so
    // this (incl. its HBM/L2 loads) overlaps other WGs finishing step t-1.
    floatx4 acc0 = {0.f, 0.f, 0.f, 0.f};
    floatx4 acc1 = {0.f, 0.f, 0.f, 0.f};
    const u16* erow = embb + ((size_t)t * BATCH + mrow) * EDIM;
#pragma unroll
    for (int s = 0; s < 16; s += 2) {
      int k0 = s * 32 + q * 8;
      int k1 = (s + 1) * 32 + q * 8;
      bf16x8 a0 = *reinterpret_cast<const bf16x8*>(erow + k0);
      bf16x8 a1 = *reinterpret_cast<const bf16x8*>(erow + k1);
      bf16x8 w0 = *reinterpret_cast<const bf16x8*>(&Blds[pbase + nlo][k0]);
      bf16x8 w1 = *reinterpret_cast<const bf16x8*>(&Blds[pbase + nlo][k1]);
      acc0 = __builtin_amdgcn_mfma_f32_16x16x32_bf16(a0, w0, acc0, 0, 0, 0);
      acc1 = __builtin_amdgcn_mfma_f32_16x16x32_bf16(a1, w1, acc1, 0, 0, 0);
    }

    // ---- wait until every WG has published h_t (flags >= t); every wave polls
    // independently. Only lanes 0..15 carry flags; others vote true.
    for (;;) {
      int ok = 1;
      if (lane < 16) {
        u64 v = __hip_atomic_load(&f8[lane], __ATOMIC_RELAXED, __HIP_MEMORY_SCOPE_AGENT);
        ok = ((u32)v >= (u32)t) && ((u32)(v >> 32) >= (u32)t);
      }
      if (__all(ok)) break;
      __builtin_amdgcn_s_sleep(1);
    }

    const u16* hcur  = hbuf + (size_t)(t & 1) * (BATCH * HDIM);
    u16*       hnext = hbuf + (size_t)((t + 1) & 1) * (BATCH * HDIM);

    // ---- h part: agent-scope (sc1, L2-bypass) loads — coherent across XCDs
    const u64* hrow = (const u64*)(hcur + (size_t)mrow * HDIM);
#pragma unroll
    for (int s = 0; s < 16; s += 2) {
      int k0 = s * 32 + q * 8;       // bf16 index in [0,512)
      int k1 = (s + 1) * 32 + q * 8;
      union { u64 qv[2]; bf16x8 v; } ua, ub;
      ua.qv[0] = __hip_atomic_load(&hrow[(k0 >> 2) + 0], __ATOMIC_RELAXED, __HIP_MEMORY_SCOPE_AGENT);
      ua.qv[1] = __hip_atomic_load(&hrow[(k0 >> 2) + 1], __ATOMIC_RELAXED, __HIP_MEMORY_SCOPE_AGENT);
      ub.qv[0] = __hip_atomic_load(&hrow[(k1 >> 2) + 0], __ATOMIC_RELAXED, __HIP_MEMORY_SCOPE_AGENT);
      ub.qv[1] = __hip_atomic_load(&hrow[(k1 >> 2) + 1], __ATOMIC_RELAXED, __HIP_MEMORY_SCOPE_AGENT);
      bf16x8 w0 = *reinterpret_cast<const bf16x8*>(&Blds[pbase + nlo][EDIM + k0]);
      bf16x8 w1 = *reinterpret_cast<const bf16x8*>(&Blds[pbase + nlo][EDIM + k1]);
      acc0 = __builtin_amdgcn_mfma_f32_16x16x32_bf16(ua.v, w0, acc0, 0, 0, 0);
      acc1 = __builtin_amdgcn_mfma_f32_16x16x32_bf16(ub.v, w1, acc1, 0, 0, 0);
    }

    // ---- wave-local transpose: same-wave DS ops are ordered, no barrier.
    floatx4 sum;
#pragma unroll
    for (int r = 0; r < 4; ++r) sum[r] = acc0[r] + acc1[r];
    *reinterpret_cast<floatx4*>(&wbuf[waveid][nlo][q * 4]) = sum;

    float pg = wbuf[waveid][ej     ][q * 4 + r0];
    float pi = wbuf[waveid][ej +  4][q * 4 + r0];
    float pf = wbuf[waveid][ej +  8][q * 4 + r0];
    float po = wbuf[waveid][ej + 12][q * 4 + r0];

    float gv = fast_tanh   (pg + bgv);
    float iv = fast_sigmoid(pi + biv);
    float fv = fast_sigmoid(pf + bfv);
    float ov = fast_sigmoid(po + bov);
    cst = gv * iv + cst * fv;
    float hv = fast_tanh(cst) * ov;

    // ---- publish path: only the bf16 h store may gate the flag.
    __hip_atomic_store(hnext + (size_t)er * HDIM + jg, f2bf(hv),
                       __ATOMIC_RELAXED, __HIP_MEMORY_SCOPE_AGENT);
    __syncthreads();   // drains all waves' h stores (vmcnt) before publish
    if (tid == 0)
      __hip_atomic_store(&flags[w], (u32)(t + 1),
                         __ATOMIC_RELAXED, __HIP_MEMORY_SCOPE_AGENT);

    // ---- off-critical-path outputs (drain at NEXT step's barrier, ~µs later)
    out[((size_t)t * BATCH + er) * HDIM + jg] = hv;          // seq
    if (t == T_STEPS - 1) {
      const size_t seqN = (size_t)T_STEPS * BATCH * HDIM;
      out[seqN + (size_t)er * HDIM + jg] = hv;               // h_T
      out[seqN + (size_t)BATCH * HDIM + (size_t)er * HDIM + jg] = cst;  // c_T
    }
  }
}

// ---------------------------------------------------------------- launch
extern "C" void kernel_launch(void* const* d_in, const int* in_sizes, int n_in,
                              void* d_out, int out_size, void* d_ws, size_t ws_size,
                              hipStream_t stream) {
  const float* emb = (const float*)d_in[0];
  const float* h0  = (const float*)d_in[1];
  const float* c0  = (const float*)d_in[2];
  const float* Wgx = (const float*)d_in[3];
  const float* Wgh = (const float*)d_in[4];
  const float* bg  = (const float*)d_in[5];
  const float* Wix = (const float*)d_in[6];
  const float* Wih = (const float*)d_in[7];
  const float* bi  = (const float*)d_in[8];
  const float* Wfx = (const float*)d_in[9];
  const float* Wfh = (const float*)d_in[10];
  const float* bf  = (const float*)d_in[11];
  const float* Wox = (const float*)d_in[12];
  const float* Woh = (const float*)d_in[13];
  const float* bo  = (const float*)d_in[14];
  float* out = (float*)d_out;

  char* ws = (char*)d_ws;
  const size_t embb_bytes = (size_t)T_STEPS * BATCH * EDIM * 2;   // 67,108,864
  u16* embb  = (u16*)ws;
  u16* hbuf  = (u16*)(ws + embb_bytes);                           // 2*32768 B
  u32* flags = (u32*)(ws + embb_bytes + 2 * (size_t)BATCH * HDIM * 2);

  static int lds_attr_set = 0;
  if (!lds_attr_set) {
    hipFuncSetAttribute(reinterpret_cast<const void*>(lstm_rec),
                        hipFuncAttributeMaxDynamicSharedMemorySize, LDS_BYTES);
    lds_attr_set = 1;
  }

  lstm_prep<<<4096, 256, 0, stream>>>(emb, embb, h0, hbuf, flags);
  lstm_rec<<<NW, WG_THREADS, LDS_BYTES, stream>>>(embb, c0,
                                                  Wgx, Wgh, bg,
                                                  Wix, Wih, bi,
                                                  Wfx, Wfh, bf,
                                                  Wox, Woh, bo,
                                                  hbuf, flags, out);
}

// Round 3
// 10752.254 us; speedup vs baseline: 2.1264x; 2.1264x over previous
//
#include <hip/hip_runtime.h>

// LSTM: T=2048, B=32, E=512, H=512, fp32 in/out.
// R3: back to R1 topology (128 WGs x 128 thr x 2 waves — R2 proved concentrating
// traffic on few CUs is 3x WORSE), plus "data-as-flag":
//   - 3-rotating h buffers in ws; producers store packed u64 (4 bf16 cols) with
//     agent scope; consumers POLL THE DATA against a bf16-NaN sentinel 0x7FC0.
//     Removes the flag store + flag-observe L3 hop (one full L3 latency/step).
//   - sentinel re-arm of buf[(t+2)%3] issued right after poll success; vmcnt(0)
//     before the data store enforces sentinel-complete-before-data-issue
//     (makes the 3-buffer rotation race-free; see proof sketch below).
//   - ZERO barriers / flags / intra-WG coupling in the loop; waves independent.
//   - h publish packed via LDS: 16 u64 stores/wave; seq out as 16B float4.
// Race proof sketch: a wave at step t has consumed h_t, so every wave finished
// its step t-1 data store, hence its step t-1 read — so buf[(t+2)%3] (=h_{t-1})
// is dead and may be sentineled. A consumer at step t+2 polling slot S has seen
// the producer's step t+1-enabling data, which was issued only AFTER its SENT(S)
// completed (vmcnt(0)) — so the consumer sees SENT or fresh data, never stale.

#define T_STEPS 2048
#define BATCH   32
#define EDIM    512
#define HDIM    512
#define NW      128   // recurrent workgroups
#define NJ      4     // h-columns per WG
#define NCOL    16    // packed gate columns per WG (4 gates * NJ)
#define WG_THREADS 128
#define BSTRIDE 1032  // 1024 + 8 pad (16B-aligned rows, kills LDS bank conflicts)
#define HQ      (BATCH * HDIM / 4)            // u64 chunks per h buffer (4096)

typedef unsigned int       u32;
typedef unsigned long long u64;
typedef unsigned short     u16;
typedef float  floatx4 __attribute__((ext_vector_type(4)));
typedef __bf16 bf16x8  __attribute__((ext_vector_type(8)));

#define SENT64 0x7FC07FC07FC07FC0ULL          // 4x bf16 NaN — unreachable from tanh*sigmoid

union BF16U { __bf16 b; u16 u; };

__device__ __forceinline__ u16 f2bf(float f) { BF16U x; x.b = (__bf16)f; return x.u; }

__device__ __forceinline__ float fast_sigmoid(float x) {
  return 1.0f / (1.0f + __expf(-x));
}
__device__ __forceinline__ float fast_tanh(float x) {
  float e = __expf(-2.0f * fabsf(x));       // e in (0,1], no overflow
  float t = (1.0f - e) / (1.0f + e);
  return x >= 0.0f ? t : -t;
}

// ---------------------------------------------------------------- phase 1
// embb: fp32 -> bf16. hbuf[0] = bf16(h_0); hbuf[1], hbuf[2] = SENTINEL.
__global__ void lstm_prep(const float* __restrict__ emb, u16* __restrict__ embb,
                          const float* __restrict__ h0, u16* __restrict__ hb) {
  const size_t n4 = (size_t)T_STEPS * BATCH * EDIM / 4;
  size_t stride = (size_t)gridDim.x * blockDim.x;
  size_t gid = (size_t)blockIdx.x * blockDim.x + threadIdx.x;
  for (size_t i = gid; i < n4; i += stride) {
    float4 v = ((const float4*)emb)[i];
    ushort4 o;
    o.x = f2bf(v.x); o.y = f2bf(v.y); o.z = f2bf(v.z); o.w = f2bf(v.w);
    ((ushort4*)embb)[i] = o;
  }
  if (gid < (size_t)BATCH * HDIM) hb[gid] = f2bf(h0[gid]);
  u64* hq = (u64*)(hb + (size_t)BATCH * HDIM);   // buffers 1 and 2
  if (gid < 2 * HQ) hq[gid] = SENT64;
}

// ---------------------------------------------------------------- phase 2
__global__ void __launch_bounds__(WG_THREADS)
lstm_rec(const u16* __restrict__ embb,
         const float* __restrict__ c0,
         const float* __restrict__ Wx0, const float* __restrict__ Wh0, const float* __restrict__ b0,
         const float* __restrict__ Wx1, const float* __restrict__ Wh1, const float* __restrict__ b1,
         const float* __restrict__ Wx2, const float* __restrict__ Wh2, const float* __restrict__ b2,
         const float* __restrict__ Wx3, const float* __restrict__ Wh3, const float* __restrict__ b3,
         u16* __restrict__ hbuf,            // [3][BATCH*HDIM] bf16 (rotating)
         float* __restrict__ out) {
  __shared__ __align__(16) __bf16 Blds[NCOL][BSTRIDE];  // [packed col][k=E|H]
  __shared__ __align__(16) float wbuf[2][NCOL][20];     // gate transpose (per wave)
  __shared__ __align__(16) float pbuf[2][16][4];        // h pack buf (per wave)

  const int tid    = threadIdx.x;
  const int w      = blockIdx.x;
  const int j0     = w * NJ;            // first h-column owned by this WG
  const int lane   = tid & 63;
  const int waveid = tid >> 6;          // 0..1 = M-tile (batch half)
  const int nlo    = lane & 15;
  const int q      = lane >> 4;
  const int mrow   = waveid * 16 + nlo; // batch row this lane loads A for

  const float* Wx[4] = {Wx0, Wx1, Wx2, Wx3};
  const float* Wh[4] = {Wh0, Wh1, Wh2, Wh3};

  // ---- stage weight slice into LDS as bf16: Blds[g*4+c][k] =
  //      k<512 ? Wx_g[k][j0+c] : Wh_g[k-512][j0+c]
  for (int g = 0; g < 4; ++g) {
    for (int base = 0; base < EDIM; base += WG_THREADS) {
      int kk = base + tid;
      float4 wx = *(const float4*)(Wx[g] + (size_t)kk * HDIM + j0);
      float4 wh = *(const float4*)(Wh[g] + (size_t)kk * HDIM + j0);
      Blds[g*NJ+0][kk] = (__bf16)wx.x;  Blds[g*NJ+0][EDIM+kk] = (__bf16)wh.x;
      Blds[g*NJ+1][kk] = (__bf16)wx.y;  Blds[g*NJ+1][EDIM+kk] = (__bf16)wh.y;
      Blds[g*NJ+2][kk] = (__bf16)wx.z;  Blds[g*NJ+2][EDIM+kk] = (__bf16)wh.z;
      Blds[g*NJ+3][kk] = (__bf16)wx.w;  Blds[g*NJ+3][EDIM+kk] = (__bf16)wh.w;
    }
  }

  // ---- per-lane epilogue state: lane owns (batch row er, h column jg).
  const int r0 = nlo >> 2;
  const int ej = nlo & 3;
  const int er = waveid * 16 + q * 4 + r0;   // batch row
  const int jg = j0 + ej;                    // global h column
  float cst = c0[(size_t)er * HDIM + jg];
  const float bgv = b0[jg], biv = b1[jg], bfv = b2[jg], bov = b3[jg];

  // ---- publisher lanes: lane<16 stores one u64 (4 bf16 cols) for one row
  const bool publane = (lane < 16);
  const int  pubrow  = waveid * 16 + nlo;                 // rows of this M-tile
  const size_t puboff = (((size_t)pubrow * HDIM + j0) >> 2);  // u64 index

  __syncthreads();   // Blds ready (only barrier in the kernel)

  u64* const hq = (u64*)hbuf;

  for (int t = 0; t < T_STEPS; ++t) {
    // ---- x-part first: gates(pre) += emb_t @ Wx slice. No h_t dependence, so
    // its HBM latency overlaps other waves finishing step t-1.
    floatx4 acc0 = {0.f, 0.f, 0.f, 0.f};
    floatx4 acc1 = {0.f, 0.f, 0.f, 0.f};
    const u16* erow = embb + ((size_t)t * BATCH + mrow) * EDIM;
#pragma unroll
    for (int s = 0; s < 16; s += 2) {
      int k0 = s * 32 + q * 8;
      int k1 = (s + 1) * 32 + q * 8;
      bf16x8 a0 = *reinterpret_cast<const bf16x8*>(erow + k0);
      bf16x8 a1 = *reinterpret_cast<const bf16x8*>(erow + k1);
      bf16x8 w0 = *reinterpret_cast<const bf16x8*>(&Blds[nlo][k0]);
      bf16x8 w1 = *reinterpret_cast<const bf16x8*>(&Blds[nlo][k1]);
      acc0 = __builtin_amdgcn_mfma_f32_16x16x32_bf16(a0, w0, acc0, 0, 0, 0);
      acc1 = __builtin_amdgcn_mfma_f32_16x16x32_bf16(a1, w1, acc1, 0, 0, 0);
    }

    const u64* hc = hq + (size_t)(t % 3) * HQ;             // consume h_t
    u64*       hn = hq + (size_t)((t + 1) % 3) * HQ;       // produce h_{t+1}
    u64*       hs = hq + (size_t)((t + 2) % 3) * HQ;       // re-arm for t+1

    // ---- data-as-flag poll: load this lane's 32 u64 h-chunks until none is
    // the sentinel. The successful poll IS the data load (no flag hop).
    const u64* hrow = hc + (size_t)mrow * (HDIM / 4);
    u64 hreg[32];
    for (;;) {
      bool ok = true;
#pragma unroll
      for (int i = 0; i < 16; ++i) {
        int base = i * 8 + q * 2;
        hreg[2*i]   = __hip_atomic_load(&hrow[base],   __ATOMIC_RELAXED, __HIP_MEMORY_SCOPE_AGENT);
        hreg[2*i+1] = __hip_atomic_load(&hrow[base+1], __ATOMIC_RELAXED, __HIP_MEMORY_SCOPE_AGENT);
        ok = ok && (hreg[2*i] != SENT64) && (hreg[2*i+1] != SENT64);
      }
      if (__all(ok)) break;
    }

    // ---- re-arm sentinel for the buffer we'll write at t+1 (dead data h_{t-1}).
    // Issued early so it completes during the MFMA/epilogue below.
    if (publane)
      __hip_atomic_store(&hs[puboff], SENT64, __ATOMIC_RELAXED, __HIP_MEMORY_SCOPE_AGENT);

    // ---- h part MFMA from registers
#pragma unroll
    for (int s = 0; s < 16; s += 2) {
      int k0 = s * 32 + q * 8;
      int k1 = (s + 1) * 32 + q * 8;
      union { u64 qv[2]; bf16x8 v; } ua, ub;
      ua.qv[0] = hreg[2*s];     ua.qv[1] = hreg[2*s+1];
      ub.qv[0] = hreg[2*s+2];   ub.qv[1] = hreg[2*s+3];
      bf16x8 w0 = *reinterpret_cast<const bf16x8*>(&Blds[nlo][EDIM + k0]);
      bf16x8 w1 = *reinterpret_cast<const bf16x8*>(&Blds[nlo][EDIM + k1]);
      acc0 = __builtin_amdgcn_mfma_f32_16x16x32_bf16(ua.v, w0, acc0, 0, 0, 0);
      acc1 = __builtin_amdgcn_mfma_f32_16x16x32_bf16(ub.v, w1, acc1, 0, 0, 0);
    }

    // ---- wave-local transpose (same-wave DS ordering, no barrier)
    floatx4 sum;
#pragma unroll
    for (int r = 0; r < 4; ++r) sum[r] = acc0[r] + acc1[r];
    *reinterpret_cast<floatx4*>(&wbuf[waveid][nlo][q * 4]) = sum;

    float pg = wbuf[waveid][ej     ][q * 4 + r0];
    float pi = wbuf[waveid][ej +  4][q * 4 + r0];
    float pf = wbuf[waveid][ej +  8][q * 4 + r0];
    float po = wbuf[waveid][ej + 12][q * 4 + r0];

    float gv = fast_tanh   (pg + bgv);
    float iv = fast_sigmoid(pi + biv);
    float fv = fast_sigmoid(pf + bfv);
    float ov = fast_sigmoid(po + bov);
    cst = gv * iv + cst * fv;
    float hv = fast_tanh(cst) * ov;

    // ---- pack h row-chunks in LDS: 4 lanes' hv -> one u64 (4 bf16 cols)
    pbuf[waveid][q * 4 + r0][ej] = hv;

    // publisher lanes gather, convert, and publish. The vmcnt(0) guarantees the
    // SENT re-arm above has COMPLETED before the data store is issued (the
    // 3-buffer rotation's soundness condition). It is ~free: the re-arm was
    // issued a full MFMA+epilogue ago, and all loads are already consumed.
    float4 hv4;
    if (publane) {
      floatx4 v4 = *reinterpret_cast<floatx4*>(&pbuf[waveid][nlo][0]);
      hv4.x = v4[0]; hv4.y = v4[1]; hv4.z = v4[2]; hv4.w = v4[3];
    }
    asm volatile("s_waitcnt vmcnt(0)" ::: "memory");
    if (publane) {
      u64 pk = (u64)f2bf(hv4.x) | ((u64)f2bf(hv4.y) << 16)
             | ((u64)f2bf(hv4.z) << 32) | ((u64)f2bf(hv4.w) << 48);
      __hip_atomic_store(&hn[puboff], pk, __ATOMIC_RELAXED, __HIP_MEMORY_SCOPE_AGENT);
      // off-critical-path: seq output as one coalesced 16B store
      *reinterpret_cast<float4*>(out + ((size_t)t * BATCH + pubrow) * HDIM + j0) = hv4;
    }
    if (t == T_STEPS - 1) {
      const size_t seqN = (size_t)T_STEPS * BATCH * HDIM;
      if (publane)
        *reinterpret_cast<float4*>(out + seqN + (size_t)pubrow * HDIM + j0) = hv4;  // h_T
      out[seqN + (size_t)BATCH * HDIM + (size_t)er * HDIM + jg] = cst;              // c_T
    }
  }
}

// ---------------------------------------------------------------- launch
extern "C" void kernel_launch(void* const* d_in, const int* in_sizes, int n_in,
                              void* d_out, int out_size, void* d_ws, size_t ws_size,
                              hipStream_t stream) {
  const float* emb = (const float*)d_in[0];
  const float* h0  = (const float*)d_in[1];
  const float* c0  = (const float*)d_in[2];
  const float* Wgx = (const float*)d_in[3];
  const float* Wgh = (const float*)d_in[4];
  const float* bg  = (const float*)d_in[5];
  const float* Wix = (const float*)d_in[6];
  const float* Wih = (const float*)d_in[7];
  const float* bi  = (const float*)d_in[8];
  const float* Wfx = (const float*)d_in[9];
  const float* Wfh = (const float*)d_in[10];
  const float* bf  = (const float*)d_in[11];
  const float* Wox = (const float*)d_in[12];
  const float* Woh = (const float*)d_in[13];
  const float* bo  = (const float*)d_in[14];
  float* out = (float*)d_out;

  char* ws = (char*)d_ws;
  const size_t embb_bytes = (size_t)T_STEPS * BATCH * EDIM * 2;   // 67,108,864
  u16* embb  = (u16*)ws;
  u16* hbuf  = (u16*)(ws + embb_bytes);                           // 3*32768 B

  lstm_prep<<<4096, 256, 0, stream>>>(emb, embb, h0, hbuf);
  lstm_rec<<<NW, WG_THREADS, 0, stream>>>(embb, c0,
                                          Wgx, Wgh, bg,
                                          Wix, Wih, bi,
                                          Wfx, Wfh, bf,
                                          Wox, Woh, bo,
                                          hbuf, out);
}